// Round 6
// baseline (3624.921 us; speedup 1.0000x reference)
//
#include <hip/hip_runtime.h>
#include <hip/hip_bf16.h>
#include <math.h>

#define BGR   8192        // graphs
#define NND   9           // nodes per graph
#define BN    73728       // BGR*NND
#define H     128
#define MH    256
#define FIN   15

typedef __bf16 bf16_t;
typedef bf16_t bf16x8 __attribute__((ext_vector_type(8)));
typedef float  f32x4  __attribute__((ext_vector_type(4)));
typedef float  f32x16 __attribute__((ext_vector_type(16)));

__device__ __forceinline__ unsigned short f2bf(float f) {
    unsigned int u = __float_as_uint(f);
    u += 0x7fff + ((u >> 16) & 1);           // RNE (inputs are finite)
    return (unsigned short)(u >> 16);
}
__device__ __forceinline__ unsigned int pkbf(float a, float b) {
    union { __hip_bfloat162 h; unsigned int u; } un;
    un.h = __float22bfloat162_rn(make_float2(a, b));
    return un.u;
}
__device__ __forceinline__ bf16x8 as_frag(int4 v) {
    union { int4 i; bf16x8 f; } u; u.i = v; return u.f;
}
__device__ __forceinline__ float fast_tanh(float v) {
    float e = __expf(2.0f * v);
    return 1.0f - __fdividef(2.0f, e + 1.0f);
}
__device__ __forceinline__ float fast_sig(float v) {
    return __fdividef(1.0f, 1.0f + __expf(-v));
}
// 16-deep XOR swizzle for 32-row MFMA fragments (2 lanes/bank = free)
__device__ __forceinline__ int sw16(int m, int k) {
    return m * 256 + ((((k >> 3) ^ (m & 15)) << 3) | (k & 7));
}
// 8-deep swizzle (16x16 kernels: gru phase, dec)
__device__ __forceinline__ int sw_off(int m, int k) {
    return m * 256 + ((((k >> 3) ^ (m & 7)) << 3) | (k & 7));
}

// ---------------------------------------------------------------- deg kernel
__global__ void deg_kernel(const int* __restrict__ edges, float* __restrict__ inv_deg) {
    int g = blockIdx.x * 256 + threadIdx.x;
    if (g >= BGR) return;
    int cnt[NND];
#pragma unroll
    for (int n = 0; n < NND; ++n) cnt[n] = 1;   // self loop
    for (int j = 0; j < 16; ++j) {
        int d = edges[g * 32 + 16 + j];
#pragma unroll
        for (int n = 0; n < NND; ++n) cnt[n] += (d == n) ? 1 : 0;
    }
#pragma unroll
    for (int n = 0; n < NND; ++n) inv_deg[g * NND + n] = 1.0f / (float)cnt[n];
}

// ---------------------------------------------------------------- encoder
__global__ void enc_kernel(const float* __restrict__ obs, const float* __restrict__ W,
                           const float* __restrict__ b, float* __restrict__ x) {
    int tid = blockIdx.x * 256 + threadIdx.x;     // BN*128 threads
    int i = tid >> 7, h = tid & 127;
    float acc = b[h];
#pragma unroll
    for (int k = 0; k < FIN; ++k) acc += obs[i * FIN + k] * W[k * H + h];
    x[i * H + h] = tanhf(acc);
}

// ---------------------------------------------------------------- weight transpose+bf16
// out: [W1T 4x256x256][W2T 4x256x256][W3T 4x128x256][WG 4x512x256][dW1T 256x128][dW2T 256x256]
// WG packed col p = w*64 + gate*16 + c  ->  (gate, h = w*16 + c), w=0..7
__global__ void wt_kernel(const float* __restrict__ W1, const float* __restrict__ W2,
                          const float* __restrict__ W3, const float* __restrict__ Wi,
                          const float* __restrict__ Wh, const float* __restrict__ dW1,
                          const float* __restrict__ dW2, unsigned short* __restrict__ out) {
    int idx = blockIdx.x * 256 + threadIdx.x;     // 1277952 total
    float v;
    if (idx < 262144) {
        int s = idx >> 16, r = idx & 65535, n = r >> 8, k = r & 255;
        v = W1[(s << 16) + (k << 8) + n];
    } else if (idx < 524288) {
        int i2 = idx - 262144;
        int s = i2 >> 16, r = i2 & 65535, n = r >> 8, k = r & 255;
        v = W2[(s << 16) + (k << 8) + n];
    } else if (idx < 655360) {
        int i3 = idx - 524288;
        int s = i3 >> 15, r = i3 & 32767, n = r >> 8, k = r & 255;
        v = W3[(s << 15) + (k << 7) + n];
    } else if (idx < 1179648) {
        int i4 = idx - 655360;                    // 0..524287
        int s = i4 >> 17, rr = i4 & 131071;
        int p = rr >> 8, k = rr & 255;
        int w = p >> 6, rem = p & 63;
        int gate = rem >> 4, c = rem & 15;
        int h = w * 16 + c;
        const int sb = s * 49152;                 // 128*384
        if (gate == 0)      v = (k < 128) ? Wi[sb + k * 384 + h]       : Wh[sb + (k - 128) * 384 + h];
        else if (gate == 1) v = (k < 128) ? Wi[sb + k * 384 + 128 + h] : Wh[sb + (k - 128) * 384 + 128 + h];
        else if (gate == 2) v = (k < 128) ? Wi[sb + k * 384 + 256 + h] : 0.f;
        else                v = (k < 128) ? 0.f                        : Wh[sb + (k - 128) * 384 + 256 + h];
    } else if (idx < 1212416) {
        int i5 = idx - 1179648;                   // dW1T [256][128]
        int n = i5 >> 7, k = i5 & 127;
        v = dW1[k * 256 + n];
    } else {
        int i6 = idx - 1212416;                   // dW2T [256][256]
        int n = i6 >> 8, k = i6 & 255;
        v = dW2[k * 256 + n];
    }
    out[idx] = f2bf(v);
}

// ---------------------------------------------------------------- fused msg MLP + GRU
// 2 graphs / block (32 rows each: 16 edges + 9 self loops + 7 pad), 1024
// threads = 16 waves. ONE m-tile + ONE f32x16 accumulator per wave in
// L1/L2/L3 -> per-wave unified regs ~<=64 -> HW can co-schedule 8 waves/SIMD
// (2 blocks/CU, 2x the 2-acc/wave R4 structure that needed 85-128 regs).
// launch_bounds (1024,4)=128 cap stays at the known spill-free point;
// occupancy upside comes from natural usage, not forcing (R2/R3 lesson:
// forced caps spill AGPR accumulators -> GBs of scratch traffic).
// Double-buffered LDS (bufA/bufB) -> 1 barrier per layer, 5 total.
// L1/L2: wave = (mt=wv&1, n-slice wv>>1). L3 (N=128): wave = (mt, nq, K-half)
// -> 8-MFMA chains, partial sums combined by the aggls LDS atomics.
// GRU: wave = (h-slice hw=wv&7, graph mh=wv>>3), gates packed in WG cols.
// Graph-locality: zero global atomics, no aggr buffer, no gru dispatch.
// 32x32 C-layout: col=lane&31, row=(reg&3)+8*(reg>>2)+4*(lane>>5);
// 16x16: col=lane&15, row=(lane>>4)*4+r.
__global__ __launch_bounds__(1024, 4) void msg_gru(
        float* __restrict__ x, const int* __restrict__ edges,
        const unsigned short* __restrict__ W1T, const float* __restrict__ b1,
        const unsigned short* __restrict__ W2T, const float* __restrict__ b2,
        const unsigned short* __restrict__ W3T, const float* __restrict__ inv_deg,
        const unsigned short* __restrict__ WG, const float* __restrict__ b3m,
        const float* __restrict__ bi, const float* __restrict__ bh) {
    __shared__ unsigned short bufA[64 * 256];   // 32 KB
    __shared__ unsigned short bufB[64 * 256];   // 32 KB
    __shared__ float aggls[2 * NND * 128];      // 9 KB binned sums
    __shared__ signed char sbin[64];            // local dst id 0..8, -1 = pad
    const int t  = threadIdx.x;
    const int g0 = blockIdx.x * 2;
    const int wv = t >> 6;        // 0..15
    const int ln = t & 63;
    const int l31 = ln & 31;
    const int lh  = ln >> 5;      // k-half selector
    const int lrow = ln & 15, lq = ln >> 4;

    // ---- zero aggls
#pragma unroll
    for (int i = 0; i < 3; ++i) {
        const int idx = t + i * 1024;
        if (idx < 2 * NND * 128) aggls[idx] = 0.f;
    }

    // ---- local dst bins for the 64 rows
    if (t < 64) {
        const int mt = t >> 5, r = t & 31;
        const int g = g0 + mt;
        int b;
        if (r < 16)      b = edges[g * 32 + 16 + r];   // explicit edge: dst
        else if (r < 25) b = r - 16;                   // self loop
        else             b = -1;                       // pad
        sbin[t] = (signed char)b;
    }

    // ---- stage A0 = bf16(concat(x[dst], x[src])) into bufA (pad rows = 0)
    {
        const int rs   = t >> 3;          // 0..127 (row, side)
        const int q    = t & 7;           // 16-col chunk within the side
        const int e    = rs & 63;         // row in block
        const int side = rs >> 6;         // 0 -> dst cols 0..127, 1 -> src
        const int mt = e >> 5, r = e & 31;
        const int g = g0 + mt;
        const int kbase = side * 128 + q * 16;
        if (r < 25) {
            int node;
            if (r < 16) node = g * NND + (side ? edges[g * 32 + r] : edges[g * 32 + 16 + r]);
            else        node = g * NND + (r - 16);
            const float* xs = x + (size_t)node * H + q * 16;
#pragma unroll
            for (int i = 0; i < 4; ++i) {
                float4 v = *(const float4*)(xs + i * 4);
                uint2 o;
                o.x = pkbf(v.x, v.y); o.y = pkbf(v.z, v.w);
                *(uint2*)(bufA + sw16(e, kbase + i * 4)) = o;
            }
        } else {
            uint2 o; o.x = 0u; o.y = 0u;
#pragma unroll
            for (int i = 0; i < 4; ++i)
                *(uint2*)(bufA + sw16(e, kbase + i * 4)) = o;
        }
    }
    __syncthreads();   // B1: staging visible

    // ---- layer 1: read bufA, write bufB. wave = (mt, n-slice)
    {
        const int mt = wv & 1, nsl = wv >> 1;   // nsl 0..7
        const int n = nsl * 32 + l31;
        const unsigned short* wp = W1T + (size_t)n * 256 + lh * 8;
        f32x16 acc;
#pragma unroll
        for (int i = 0; i < 16; ++i) acc[i] = 0.f;
#pragma unroll
        for (int ks = 0; ks < 16; ++ks) {
            const int kk = ks * 16 + lh * 8;
            bf16x8 a = as_frag(*(const int4*)(bufA + sw16(mt * 32 + l31, kk)));
            bf16x8 bw = as_frag(*(const int4*)(wp + ks * 16));
            acc = __builtin_amdgcn_mfma_f32_32x32x16_bf16(a, bw, acc, 0, 0, 0);
        }
        const float bias = b1[n];
#pragma unroll
        for (int reg = 0; reg < 16; ++reg) {
            const int mrow = (reg & 3) + ((reg >> 2) << 3) + (lh << 2);
            bufB[sw16(mt * 32 + mrow, n)] = f2bf(fast_tanh(acc[reg] + bias));
        }
    }
    __syncthreads();   // B2: L1 output visible

    // ---- layer 2: read bufB, write bufA
    {
        const int mt = wv & 1, nsl = wv >> 1;
        const int n = nsl * 32 + l31;
        const unsigned short* wp = W2T + (size_t)n * 256 + lh * 8;
        f32x16 acc;
#pragma unroll
        for (int i = 0; i < 16; ++i) acc[i] = 0.f;
#pragma unroll
        for (int ks = 0; ks < 16; ++ks) {
            const int kk = ks * 16 + lh * 8;
            bf16x8 a = as_frag(*(const int4*)(bufB + sw16(mt * 32 + l31, kk)));
            bf16x8 bw = as_frag(*(const int4*)(wp + ks * 16));
            acc = __builtin_amdgcn_mfma_f32_32x32x16_bf16(a, bw, acc, 0, 0, 0);
        }
        const float bias = b2[n];
#pragma unroll
        for (int reg = 0; reg < 16; ++reg) {
            const int mrow = (reg & 3) + ((reg >> 2) << 3) + (lh << 2);
            bufA[sw16(mt * 32 + mrow, n)] = f2bf(fast_tanh(acc[reg] + bias));
        }
    }
    __syncthreads();   // B3: L2 output visible

    // ---- layer 3: read bufA; N=128; wave = (mt, nq, K-half); partial sums
    //      combined via aggls LDS atomics (zeroed pre-B1)
    {
        const int mt = wv & 1, nq = (wv >> 1) & 3, kh = wv >> 3;
        const int n = nq * 32 + l31;
        const unsigned short* wp = W3T + (size_t)n * 256 + lh * 8;
        f32x16 acc;
#pragma unroll
        for (int i = 0; i < 16; ++i) acc[i] = 0.f;
#pragma unroll
        for (int ks2 = 0; ks2 < 8; ++ks2) {
            const int ks = kh * 8 + ks2;
            const int kk = ks * 16 + lh * 8;
            bf16x8 a = as_frag(*(const int4*)(bufA + sw16(mt * 32 + l31, kk)));
            bf16x8 bw = as_frag(*(const int4*)(wp + ks * 16));
            acc = __builtin_amdgcn_mfma_f32_32x32x16_bf16(a, bw, acc, 0, 0, 0);
        }
        const int abase = mt * NND * 128 + n;
#pragma unroll
        for (int reg = 0; reg < 16; ++reg) {
            const int mrow = (reg & 3) + ((reg >> 2) << 3) + (lh << 2);
            const int bv = sbin[mt * 32 + mrow];
            if (bv >= 0) atomicAdd(&aggls[abase + bv * 128], acc[reg]);
        }
    }
    __syncthreads();   // B4: binned sums complete

    // ---- GRU stage: A[32][256] bf16 into bufB rows 0..31 = [aggr*inv+b3 | x]
    {
        const int r = t >> 5;          // 0..31
        const int c = t & 31;          // 8-col chunk
        const int g = r >> 4, lm = r & 15;
        const int k0 = c * 8;
        if (lm < NND) {
            const int node = (g0 + g) * NND + lm;
            float vals[8];
            if (c < 16) {
                const float invd = inv_deg[node];
                const float* ap = aggls + (g * NND + lm) * 128 + k0;
                float4 a0 = *(const float4*)(ap);
                float4 a1 = *(const float4*)(ap + 4);
                float4 b0 = *(const float4*)(b3m + k0);
                float4 b1v = *(const float4*)(b3m + k0 + 4);
                vals[0] = a0.x * invd + b0.x;  vals[1] = a0.y * invd + b0.y;
                vals[2] = a0.z * invd + b0.z;  vals[3] = a0.w * invd + b0.w;
                vals[4] = a1.x * invd + b1v.x; vals[5] = a1.y * invd + b1v.y;
                vals[6] = a1.z * invd + b1v.z; vals[7] = a1.w * invd + b1v.w;
            } else {
                const float* xp = x + (size_t)node * H + (k0 - 128);
                float4 a0 = *(const float4*)(xp);
                float4 a1 = *(const float4*)(xp + 4);
                vals[0] = a0.x; vals[1] = a0.y; vals[2] = a0.z; vals[3] = a0.w;
                vals[4] = a1.x; vals[5] = a1.y; vals[6] = a1.z; vals[7] = a1.w;
            }
            int4 o;
            o.x = (int)pkbf(vals[0], vals[1]);
            o.y = (int)pkbf(vals[2], vals[3]);
            o.z = (int)pkbf(vals[4], vals[5]);
            o.w = (int)pkbf(vals[6], vals[7]);
            *(int4*)(bufB + sw_off(r, k0)) = o;
        } else {
            int4 z; z.x = 0; z.y = 0; z.z = 0; z.w = 0;
            *(int4*)(bufB + sw_off(r, k0)) = z;
        }
    }
    __syncthreads();   // B5: GRU A staged

    // ---- GRU GEMM (16x16x32): wave = (h-slice hw, graph mh) + gate epilogue
    {
        const int hw = wv & 7, mh = wv >> 3;
        const f32x4 zero = {0.f, 0.f, 0.f, 0.f};
        f32x4 gacc[4];    // [gate]
#pragma unroll
        for (int j = 0; j < 4; ++j) gacc[j] = zero;
        const unsigned short* wgp = WG + (size_t)(hw * 64 + lrow) * 256;
#pragma unroll
        for (int kq = 0; kq < 8; ++kq) {
            const int ko = kq * 32 + lq * 8;
            bf16x8 a = as_frag(*(const int4*)(bufB + sw_off(mh * 16 + lrow, ko)));
#pragma unroll
            for (int g = 0; g < 4; ++g) {
                bf16x8 bw = as_frag(*(const int4*)(wgp + (size_t)g * 4096 + ko));
                gacc[g] = __builtin_amdgcn_mfma_f32_16x16x32_bf16(a, bw, gacc[g], 0, 0, 0);
            }
        }
        const int h = hw * 16 + lrow;
        const float b_r = bi[h] + bh[h];
        const float b_z = bi[128 + h] + bh[128 + h];
        const float b_n = bi[256 + h];
        const float b_h = bh[256 + h];
#pragma unroll
        for (int r = 0; r < 4; ++r) {
            const int lm = lq * 4 + r;
            if (lm < NND) {
                const int node = (g0 + mh) * NND + lm;
                const float irhr = gacc[0][r] + b_r;
                const float izhz = gacc[1][r] + b_z;
                const float inn  = gacc[2][r] + b_n;
                const float hn   = gacc[3][r] + b_h;
                const float rg = fast_sig(irhr);
                const float zg = fast_sig(izhz);
                const float ng = fast_tanh(inn + rg * hn);
                float* xp = x + (size_t)node * H + h;
                const float xo = *xp;
                *xp = (1.f - zg) * ng + zg * xo;
            }
        }
    }
}

// ---------------------------------------------------------------- decoder via MFMA (64 masked ids / block)
__global__ __launch_bounds__(256, 4) void dec_mfma(
        const float* __restrict__ x,
        const unsigned short* __restrict__ W1T, const float* __restrict__ b1,
        const unsigned short* __restrict__ W2T, const float* __restrict__ b2,
        const float* __restrict__ W3, const float* __restrict__ b3,
        float* __restrict__ out) {
    __shared__ unsigned short buf[64 * 256];   // 32 KB
    const int t = threadIdx.x;
    const int id0 = blockIdx.x * 64;
    const int wv = t >> 6, ln = t & 63, lrow = ln & 15, lq = ln >> 4;
    const int nbase = wv * 64;

    // stage bf16(x) for 64 masked ids into buf[:, 0:128]
    {
        const int m = t >> 2, q = t & 3;
        const int id = id0 + m;
        const int node = (id >> 3) * NND + (id & 7);
        const float* src = x + (size_t)node * H + q * 32;
#pragma unroll
        for (int i = 0; i < 8; ++i) {
            float4 v = *(const float4*)(src + i * 4);
            uint2 o; o.x = pkbf(v.x, v.y); o.y = pkbf(v.z, v.w);
            *(uint2*)(buf + sw_off(m, q * 32 + i * 4)) = o;
        }
    }
    __syncthreads();

    const f32x4 zero = {0.f, 0.f, 0.f, 0.f};

    // ---- layer 1: K=128 -> 256 cols
    {
        f32x4 acc[4][4];
#pragma unroll
        for (int i = 0; i < 4; ++i)
#pragma unroll
            for (int j = 0; j < 4; ++j) acc[i][j] = zero;
#pragma unroll
        for (int kq = 0; kq < 4; ++kq) {
            const int ko = kq * 32 + lq * 8;
            bf16x8 af[4], bfr[4];
#pragma unroll
            for (int tm = 0; tm < 4; ++tm)
                af[tm] = as_frag(*(const int4*)(buf + sw_off(tm * 16 + lrow, ko)));
#pragma unroll
            for (int tn = 0; tn < 4; ++tn)
                bfr[tn] = as_frag(*(const int4*)(W1T + (size_t)(nbase + tn * 16 + lrow) * 128 + ko));
#pragma unroll
            for (int tm = 0; tm < 4; ++tm)
#pragma unroll
                for (int tn = 0; tn < 4; ++tn)
                    acc[tm][tn] = __builtin_amdgcn_mfma_f32_16x16x32_bf16(af[tm], bfr[tn], acc[tm][tn], 0, 0, 0);
        }
        __syncthreads();
#pragma unroll
        for (int tn = 0; tn < 4; ++tn) {
            const int n = nbase + tn * 16 + lrow;
            const float bias = b1[n];
#pragma unroll
            for (int tm = 0; tm < 4; ++tm)
#pragma unroll
                for (int r = 0; r < 4; ++r) {
                    const int m = tm * 16 + lq * 4 + r;
                    buf[sw_off(m, n)] = f2bf(fast_tanh(acc[tm][tn][r] + bias));
                }
        }
    }
    __syncthreads();

    // ---- layer 2: K=256 -> 256 cols
    {
        f32x4 acc[4][4];
#pragma unroll
        for (int i = 0; i < 4; ++i)
#pragma unroll
            for (int j = 0; j < 4; ++j) acc[i][j] = zero;
#pragma unroll
        for (int kq = 0; kq < 8; ++kq) {
            const int ko = kq * 32 + lq * 8;
            bf16x8 af[4], bfr[4];
#pragma unroll
            for (int tm = 0; tm < 4; ++tm)
                af[tm] = as_frag(*(const int4*)(buf + sw_off(tm * 16 + lrow, ko)));
#pragma unroll
            for (int tn = 0; tn < 4; ++tn)
                bfr[tn] = as_frag(*(const int4*)(W2T + (size_t)(nbase + tn * 16 + lrow) * 256 + ko));
#pragma unroll
            for (int tm = 0; tm < 4; ++tm)
#pragma unroll
                for (int tn = 0; tn < 4; ++tn)
                    acc[tm][tn] = __builtin_amdgcn_mfma_f32_16x16x32_bf16(af[tm], bfr[tn], acc[tm][tn], 0, 0, 0);
        }
        __syncthreads();
#pragma unroll
        for (int tn = 0; tn < 4; ++tn) {
            const int n = nbase + tn * 16 + lrow;
            const float bias = b2[n];
#pragma unroll
            for (int tm = 0; tm < 4; ++tm)
#pragma unroll
                for (int r = 0; r < 4; ++r) {
                    const int m = tm * 16 + lq * 4 + r;
                    buf[sw_off(m, n)] = f2bf(fast_tanh(acc[tm][tn][r] + bias));
                }
        }
    }
    __syncthreads();

    // ---- layer 3: 256 -> 1, 4 threads per id, shuffle reduce
    {
        const int m = t >> 2, p = t & 3;
        float s = 0.f;
#pragma unroll
        for (int i = 0; i < 64; ++i) {
            const int k = p * 64 + i;
            const float a = __uint_as_float((unsigned int)buf[sw_off(m, k)] << 16);
            s += a * W3[k];
        }
        s += __shfl_xor(s, 1);
        s += __shfl_xor(s, 2);
        if (p == 0) out[id0 + m] = s + b3[0];
    }
}

// ---------------------------------------------------------------- launch
extern "C" void kernel_launch(void* const* d_in, const int* in_sizes, int n_in,
                              void* d_out, int out_size, void* d_ws, size_t ws_size,
                              hipStream_t stream) {
    const float* obs    = (const float*)d_in[0];
    const int*   edges  = (const int*)  d_in[1];
    const float* enc_W  = (const float*)d_in[2];
    const float* enc_b  = (const float*)d_in[3];
    const float* msg_W1 = (const float*)d_in[4];
    const float* msg_b1 = (const float*)d_in[5];
    const float* msg_W2 = (const float*)d_in[6];
    const float* msg_b2 = (const float*)d_in[7];
    const float* msg_W3 = (const float*)d_in[8];
    const float* msg_b3 = (const float*)d_in[9];
    const float* gru_Wi = (const float*)d_in[10];
    const float* gru_Wh = (const float*)d_in[11];
    const float* gru_bi = (const float*)d_in[12];
    const float* gru_bh = (const float*)d_in[13];
    const float* dec_W1 = (const float*)d_in[14];
    const float* dec_b1 = (const float*)d_in[15];
    const float* dec_W2 = (const float*)d_in[16];
    const float* dec_b2 = (const float*)d_in[17];
    const float* dec_W3 = (const float*)d_in[18];
    const float* dec_b3 = (const float*)d_in[19];

    float* x       = (float*)d_ws;                 // BN*128
    float* inv_deg = x + (size_t)BN * H;           // BN
    unsigned short* wbf = (unsigned short*)(inv_deg + BN);   // 1277952 bf16

    deg_kernel<<<(BGR + 255) / 256, 256, 0, stream>>>(edges, inv_deg);
    wt_kernel<<<1277952 / 256, 256, 0, stream>>>(msg_W1, msg_W2, msg_W3, gru_Wi, gru_Wh,
                                                 dec_W1, dec_W2, wbf);
    enc_kernel<<<BN * H / 256, 256, 0, stream>>>(obs, enc_W, enc_b, x);

    for (int s = 0; s < 4; ++s) {
        const unsigned short* W1T = wbf + (size_t)s * 65536;
        const unsigned short* W2T = wbf + 262144 + (size_t)s * 65536;
        const unsigned short* W3T = wbf + 524288 + (size_t)s * 32768;
        const unsigned short* WGs = wbf + 655360 + (size_t)s * 131072;
        msg_gru<<<BGR / 2, 1024, 0, stream>>>(
            x, edges,
            W1T, msg_b1 + (size_t)s * 256,
            W2T, msg_b2 + (size_t)s * 256,
            W3T, inv_deg,
            WGs, msg_b3 + (size_t)s * 128,
            gru_bi + (size_t)s * 384, gru_bh + (size_t)s * 384);
    }

    dec_mfma<<<BGR * 8 / 64, 256, 0, stream>>>(
        x, wbf + 1179648, dec_b1, wbf + 1212416, dec_b2, dec_W3, dec_b3, (float*)d_out);
}

// Round 7
// 1884.792 us; speedup vs baseline: 1.9232x; 1.9232x over previous
//
#include <hip/hip_runtime.h>
#include <hip/hip_bf16.h>
#include <math.h>

#define BGR   8192        // graphs
#define NND   9           // nodes per graph
#define BN    73728       // BGR*NND
#define H     128
#define MH    256
#define FIN   15

typedef __bf16 bf16_t;
typedef bf16_t bf16x8 __attribute__((ext_vector_type(8)));
typedef float  f32x4  __attribute__((ext_vector_type(4)));
typedef float  f32x16 __attribute__((ext_vector_type(16)));

__device__ __forceinline__ unsigned short f2bf(float f) {
    unsigned int u = __float_as_uint(f);
    u += 0x7fff + ((u >> 16) & 1);           // RNE (inputs are finite)
    return (unsigned short)(u >> 16);
}
__device__ __forceinline__ unsigned int pkbf(float a, float b) {
    union { __hip_bfloat162 h; unsigned int u; } un;
    un.h = __float22bfloat162_rn(make_float2(a, b));
    return un.u;
}
__device__ __forceinline__ bf16x8 as_frag(int4 v) {
    union { int4 i; bf16x8 f; } u; u.i = v; return u.f;
}
__device__ __forceinline__ float fast_tanh(float v) {
    float e = __expf(2.0f * v);
    return 1.0f - __fdividef(2.0f, e + 1.0f);
}
__device__ __forceinline__ float fast_sig(float v) {
    return __fdividef(1.0f, 1.0f + __expf(-v));
}
// 16-deep XOR swizzle for 32-row MFMA fragments (2 lanes/bank = free)
__device__ __forceinline__ int sw16(int m, int k) {
    return m * 256 + ((((k >> 3) ^ (m & 15)) << 3) | (k & 7));
}
// 8-deep swizzle (16x16 tiles: gru, dec)
__device__ __forceinline__ int sw_off(int m, int k) {
    return m * 256 + ((((k >> 3) ^ (m & 7)) << 3) | (k & 7));
}

// ---------------------------------------------------------------- weight transpose+bf16
// out: [W1T 4x256x256][W2T 4x256x256][W3T 4x128x256][WG 4x512x256][dW1T 256x128][dW2T 256x256]
// WG packed col p = w*64 + gate*16 + c  ->  (gate, h = w*16 + c), w=0..7
__global__ void wt_kernel(const float* __restrict__ W1, const float* __restrict__ W2,
                          const float* __restrict__ W3, const float* __restrict__ Wi,
                          const float* __restrict__ Wh, const float* __restrict__ dW1,
                          const float* __restrict__ dW2, unsigned short* __restrict__ out) {
    int idx = blockIdx.x * 256 + threadIdx.x;     // 1277952 total
    float v;
    if (idx < 262144) {
        int s = idx >> 16, r = idx & 65535, n = r >> 8, k = r & 255;
        v = W1[(s << 16) + (k << 8) + n];
    } else if (idx < 524288) {
        int i2 = idx - 262144;
        int s = i2 >> 16, r = i2 & 65535, n = r >> 8, k = r & 255;
        v = W2[(s << 16) + (k << 8) + n];
    } else if (idx < 655360) {
        int i3 = idx - 524288;
        int s = i3 >> 15, r = i3 & 32767, n = r >> 8, k = r & 255;
        v = W3[(s << 15) + (k << 7) + n];
    } else if (idx < 1179648) {
        int i4 = idx - 655360;                    // 0..524287
        int s = i4 >> 17, rr = i4 & 131071;
        int p = rr >> 8, k = rr & 255;
        int w = p >> 6, rem = p & 63;
        int gate = rem >> 4, c = rem & 15;
        int h = w * 16 + c;
        const int sb = s * 49152;                 // 128*384
        if (gate == 0)      v = (k < 128) ? Wi[sb + k * 384 + h]       : Wh[sb + (k - 128) * 384 + h];
        else if (gate == 1) v = (k < 128) ? Wi[sb + k * 384 + 128 + h] : Wh[sb + (k - 128) * 384 + 128 + h];
        else if (gate == 2) v = (k < 128) ? Wi[sb + k * 384 + 256 + h] : 0.f;
        else                v = (k < 128) ? 0.f                        : Wh[sb + (k - 128) * 384 + 256 + h];
    } else if (idx < 1212416) {
        int i5 = idx - 1179648;                   // dW1T [256][128]
        int n = i5 >> 7, k = i5 & 127;
        v = dW1[k * 256 + n];
    } else {
        int i6 = idx - 1212416;                   // dW2T [256][256]
        int n = i6 >> 8, k = i6 & 255;
        v = dW2[k * 256 + n];
    }
    out[idx] = f2bf(v);
}

// ---------------------------------------------------------------- fully fused GNN
// One block = 2 graphs through the ENTIRE network: enc -> 4x(msg MLP + GRU)
// -> dec. Everything is graph-local, so x (18 nodes x 128 f32) lives in LDS
// across all steps: no global x round-trips, no aggr buffer, no atomics,
// 9 dispatches -> 2. Single in-place 32 KB GEMM buffer (reads-done barrier
// before each epilogue write); LDS ~42 KB -> 2 blocks/CU at the proven
// spill-free (512,4) cap (R2/R3: tighter caps spill AGPR accumulators).
// msg layers: 32x32x16 MFMA, wave wv owns n-tile wv*32, both 32-row m-tiles
// (L1/L2); L3 wave=(graph,m-tile nq), 9-bin register reduction writes
// [aggr*inv_deg + b3 | x] bf16 directly into the GRU A region (buf rows
// 0..31, sw_off layout). GRU: 16x16x32, wave wv owns packed WG cols (all 4
// gates of h-slice wv*16..+15); epilogue updates xls in place. Decoder:
// 16 masked ids/block via 16x16 MFMA into disjoint buf row bands (no
// reads-done barriers). 32x32 C-layout: col=lane&31,
// row=(reg&3)+8*(reg>>2)+4*(lane>>5); 16x16: col=lane&15, row=(lane>>4)*4+r.
__global__ __launch_bounds__(512, 4) void gnn_fused(
        const float* __restrict__ obs, const int* __restrict__ edges,
        const float* __restrict__ enc_W, const float* __restrict__ enc_b,
        const unsigned short* __restrict__ wbf,
        const float* __restrict__ msg_b1, const float* __restrict__ msg_b2,
        const float* __restrict__ msg_b3,
        const float* __restrict__ gru_bi, const float* __restrict__ gru_bh,
        const float* __restrict__ dec_b1, const float* __restrict__ dec_b2,
        const float* __restrict__ dec_W3, const float* __restrict__ dec_b3,
        float* __restrict__ out) {
    __shared__ unsigned short buf[64 * 256];    // 32 KB GEMM buffer
    __shared__ float xls[18 * 128];             // 9 KB node state (f32)
    __shared__ float sdeg[18];                  // inv degree
    __shared__ signed char sld[64], sls[64];    // per-row dst/src local id, -1 pad
    const int t  = threadIdx.x;
    const int g0 = blockIdx.x * 2;
    const int wv = t >> 6;        // 0..7
    const int ln = t & 63;
    const int l31 = ln & 31;
    const int lh  = ln >> 5;      // k-half selector
    const int lrow = ln & 15, lq = ln >> 4;

    // ---- init: edge tables + inv_deg
    if (t < 64) {
        const int mt = t >> 5, r = t & 31;
        const int g = g0 + mt;
        int d, sv;
        if (r < 16)      { d = edges[g * 32 + 16 + r]; sv = edges[g * 32 + r]; }
        else if (r < 25) { d = r - 16; sv = r - 16; }
        else             { d = -1; sv = -1; }
        sld[t] = (signed char)d; sls[t] = (signed char)sv;
    }
    if (t < 18) {
        const int g = g0 + t / 9, n = t % 9;
        int c = 1;
        for (int j = 0; j < 16; ++j) c += (edges[g * 32 + 16 + j] == n) ? 1 : 0;
        sdeg[t] = 1.0f / (float)c;
    }
    // ---- encoder: xls = tanh(obs @ enc_W + enc_b), 18 nodes x 128
    for (int i = t; i < 18 * 128; i += 512) {
        const int nd = i >> 7, h = i & 127;
        const int g = g0 + nd / 9, lnode = nd % 9;
        const float* op = obs + (size_t)g * 135 + lnode * 15;
        float a = enc_b[h];
#pragma unroll
        for (int k = 0; k < FIN; ++k) a += op[k] * enc_W[k * H + h];
        xls[i] = tanhf(a);
    }
    __syncthreads();   // S0: init + enc visible

#pragma unroll 1
    for (int s = 0; s < 4; ++s) {
        const unsigned short* W1T = wbf + (size_t)s * 65536;
        const unsigned short* W2T = wbf + 262144 + (size_t)s * 65536;
        const unsigned short* W3T = wbf + 524288 + (size_t)s * 32768;
        const unsigned short* WG  = wbf + 655360 + (size_t)s * 131072;
        const float* b1p = msg_b1 + (size_t)s * 256;
        const float* b2p = msg_b2 + (size_t)s * 256;
        const float* b3p = msg_b3 + (size_t)s * 128;
        const float* bip = gru_bi + (size_t)s * 384;
        const float* bhp = gru_bh + (size_t)s * 384;

        // ---- stage A0 = bf16([x[dst] | x[src]]) from xls (pad rows = 0)
        {
            const int rowside = t >> 2, q = t & 3;
            const int e = rowside & 63, side = rowside >> 6;
            const int mt = e >> 5;
            const int node = side ? (int)sls[e] : (int)sld[e];
            const int kbase = side * 128 + q * 32;
            if (node >= 0) {
                const float* xp = xls + (mt * 9 + node) * 128 + q * 32;
#pragma unroll
                for (int i = 0; i < 8; ++i) {
                    float4 v = *(const float4*)(xp + i * 4);
                    uint2 o; o.x = pkbf(v.x, v.y); o.y = pkbf(v.z, v.w);
                    *(uint2*)(buf + sw16(e, kbase + i * 4)) = o;
                }
            } else {
                uint2 o; o.x = 0u; o.y = 0u;
#pragma unroll
                for (int i = 0; i < 8; ++i)
                    *(uint2*)(buf + sw16(e, kbase + i * 4)) = o;
            }
        }
        __syncthreads();   // S1: staging visible

        // ---- layer 1 (in-place)
        {
            f32x16 acc0, acc1;
#pragma unroll
            for (int i = 0; i < 16; ++i) { acc0[i] = 0.f; acc1[i] = 0.f; }
            const unsigned short* wp = W1T + (size_t)(wv * 32 + l31) * 256 + lh * 8;
#pragma unroll
            for (int ks = 0; ks < 16; ++ks) {
                const int kk = ks * 16 + lh * 8;
                bf16x8 a0 = as_frag(*(const int4*)(buf + sw16(l31, kk)));
                bf16x8 a1 = as_frag(*(const int4*)(buf + sw16(32 + l31, kk)));
                bf16x8 bw = as_frag(*(const int4*)(wp + ks * 16));
                acc0 = __builtin_amdgcn_mfma_f32_32x32x16_bf16(a0, bw, acc0, 0, 0, 0);
                acc1 = __builtin_amdgcn_mfma_f32_32x32x16_bf16(a1, bw, acc1, 0, 0, 0);
            }
            __syncthreads();   // S2: reads done
            const int n = wv * 32 + l31;
            const float bias = b1p[n];
#pragma unroll
            for (int reg = 0; reg < 16; ++reg) {
                const int mrow = (reg & 3) + ((reg >> 2) << 3) + (lh << 2);
                buf[sw16(mrow, n)]      = f2bf(fast_tanh(acc0[reg] + bias));
                buf[sw16(32 + mrow, n)] = f2bf(fast_tanh(acc1[reg] + bias));
            }
        }
        __syncthreads();   // S3: L1 out visible

        // ---- layer 2 (in-place)
        {
            f32x16 acc0, acc1;
#pragma unroll
            for (int i = 0; i < 16; ++i) { acc0[i] = 0.f; acc1[i] = 0.f; }
            const unsigned short* wp = W2T + (size_t)(wv * 32 + l31) * 256 + lh * 8;
#pragma unroll
            for (int ks = 0; ks < 16; ++ks) {
                const int kk = ks * 16 + lh * 8;
                bf16x8 a0 = as_frag(*(const int4*)(buf + sw16(l31, kk)));
                bf16x8 a1 = as_frag(*(const int4*)(buf + sw16(32 + l31, kk)));
                bf16x8 bw = as_frag(*(const int4*)(wp + ks * 16));
                acc0 = __builtin_amdgcn_mfma_f32_32x32x16_bf16(a0, bw, acc0, 0, 0, 0);
                acc1 = __builtin_amdgcn_mfma_f32_32x32x16_bf16(a1, bw, acc1, 0, 0, 0);
            }
            __syncthreads();   // S4: reads done
            const int n = wv * 32 + l31;
            const float bias = b2p[n];
#pragma unroll
            for (int reg = 0; reg < 16; ++reg) {
                const int mrow = (reg & 3) + ((reg >> 2) << 3) + (lh << 2);
                buf[sw16(mrow, n)]      = f2bf(fast_tanh(acc0[reg] + bias));
                buf[sw16(32 + mrow, n)] = f2bf(fast_tanh(acc1[reg] + bias));
            }
        }
        __syncthreads();   // S5: L2 out visible

        // ---- layer 3: N=128, wave (mt = graph = wv&1, nq = wv>>1);
        //      9-bin register reduce -> write GRU A cols 0..127 directly
        {
            const int mt = wv & 1, nq = wv >> 1;
            const int n = nq * 32 + l31;
            f32x16 acc;
#pragma unroll
            for (int i = 0; i < 16; ++i) acc[i] = 0.f;
            const unsigned short* wp = W3T + (size_t)n * 256 + lh * 8;
#pragma unroll
            for (int ks = 0; ks < 16; ++ks) {
                const int kk = ks * 16 + lh * 8;
                bf16x8 a = as_frag(*(const int4*)(buf + sw16(mt * 32 + l31, kk)));
                bf16x8 bw = as_frag(*(const int4*)(wp + ks * 16));
                acc = __builtin_amdgcn_mfma_f32_32x32x16_bf16(a, bw, acc, 0, 0, 0);
            }
            __syncthreads();   // S6: L3 reads done, buf rows 0..31 free
            int binr[16];
#pragma unroll
            for (int reg = 0; reg < 16; ++reg) {
                const int mrow = (reg & 3) + ((reg >> 2) << 3) + (lh << 2);
                binr[reg] = (int)sld[mt * 32 + mrow];
            }
            const float bias3 = b3p[n];
#pragma unroll
            for (int b = 0; b < NND; ++b) {
                float sv = 0.f;
#pragma unroll
                for (int reg = 0; reg < 16; ++reg)
                    sv = (binr[reg] == b) ? sv + acc[reg] : sv;
                sv += __shfl_xor(sv, 32);   // combine lh halves (rows)
                if (lh == (b & 1))
                    buf[sw_off(mt * 16 + b, n)] = f2bf(sv * sdeg[mt * 9 + b] + bias3);
            }
            // x-half of GRU A (cols 128..255) from xls
            if (t < 256) {
                const int r = t >> 3, c = t & 7;
                const int g = r >> 4, lm = r & 15;
                if (lm < NND) {
                    const float* xp = xls + (g * 9 + lm) * 128 + c * 16;
                    float4 v0 = *(const float4*)(xp);
                    float4 v1 = *(const float4*)(xp + 4);
                    float4 v2 = *(const float4*)(xp + 8);
                    float4 v3 = *(const float4*)(xp + 12);
                    int4 o0, o1;
                    o0.x = (int)pkbf(v0.x, v0.y); o0.y = (int)pkbf(v0.z, v0.w);
                    o0.z = (int)pkbf(v1.x, v1.y); o0.w = (int)pkbf(v1.z, v1.w);
                    o1.x = (int)pkbf(v2.x, v2.y); o1.y = (int)pkbf(v2.z, v2.w);
                    o1.z = (int)pkbf(v3.x, v3.y); o1.w = (int)pkbf(v3.z, v3.w);
                    *(int4*)(buf + sw_off(r, 128 + c * 16)) = o0;
                    *(int4*)(buf + sw_off(r, 128 + c * 16 + 8)) = o1;
                }
                // pad rows: garbage is fine, their GRU outputs are discarded
            }
        }
        __syncthreads();   // S7: GRU A staged

        // ---- GRU GEMM (16x16x32) + gate epilogue, xls updated in place
        {
            const f32x4 zero = {0.f, 0.f, 0.f, 0.f};
            f32x4 gacc[2][4];    // [graph][gate]
#pragma unroll
            for (int i = 0; i < 2; ++i)
#pragma unroll
                for (int j = 0; j < 4; ++j) gacc[i][j] = zero;
            const unsigned short* wgp = WG + (size_t)(wv * 64 + lrow) * 256;
#pragma unroll
            for (int kq = 0; kq < 8; ++kq) {
                const int ko = kq * 32 + lq * 8;
                bf16x8 a0 = as_frag(*(const int4*)(buf + sw_off(lrow, ko)));
                bf16x8 a1 = as_frag(*(const int4*)(buf + sw_off(16 + lrow, ko)));
#pragma unroll
                for (int g = 0; g < 4; ++g) {
                    bf16x8 bw = as_frag(*(const int4*)(wgp + (size_t)g * 4096 + ko));
                    gacc[0][g] = __builtin_amdgcn_mfma_f32_16x16x32_bf16(a0, bw, gacc[0][g], 0, 0, 0);
                    gacc[1][g] = __builtin_amdgcn_mfma_f32_16x16x32_bf16(a1, bw, gacc[1][g], 0, 0, 0);
                }
            }
            const int h = wv * 16 + lrow;
            const float b_r = bip[h] + bhp[h];
            const float b_z = bip[128 + h] + bhp[128 + h];
            const float b_n = bip[256 + h];
            const float b_h = bhp[256 + h];
#pragma unroll
            for (int tm = 0; tm < 2; ++tm) {
#pragma unroll
                for (int r = 0; r < 4; ++r) {
                    const int lm = lq * 4 + r;
                    if (lm < NND) {
                        const int idx = (tm * 9 + lm) * 128 + h;
                        const float irhr = gacc[tm][0][r] + b_r;
                        const float izhz = gacc[tm][1][r] + b_z;
                        const float inn  = gacc[tm][2][r] + b_n;
                        const float hn   = gacc[tm][3][r] + b_h;
                        const float rg = fast_sig(irhr);
                        const float zg = fast_sig(izhz);
                        const float ng = fast_tanh(inn + rg * hn);
                        const float xo = xls[idx];
                        xls[idx] = (1.f - zg) * ng + zg * xo;
                    }
                }
            }
        }
        __syncthreads();   // S8: x updated, buf free
    }

    // ================ decoder: 16 masked ids (2 graphs x nodes 0..7) ======
    // stage bf16(x) into buf rows 0..15
    if (t < 64) {
        const int m = t >> 2, q = t & 3;
        const int g = m >> 3, nd = m & 7;
        const float* xp = xls + (g * 9 + nd) * 128 + q * 32;
#pragma unroll
        for (int i = 0; i < 8; ++i) {
            float4 v = *(const float4*)(xp + i * 4);
            uint2 o; o.x = pkbf(v.x, v.y); o.y = pkbf(v.z, v.w);
            *(uint2*)(buf + sw_off(m, q * 32 + i * 4)) = o;
        }
    }
    __syncthreads();

    // dec layer 1: K=128 -> N=256, out rows 16..31 (disjoint band, no hazard)
    {
        const f32x4 zero = {0.f, 0.f, 0.f, 0.f};
        f32x4 dacc[2] = {zero, zero};
        const unsigned short* dW1T = wbf + 1179648;
#pragma unroll
        for (int kq = 0; kq < 4; ++kq) {
            const int ko = kq * 32 + lq * 8;
            bf16x8 af = as_frag(*(const int4*)(buf + sw_off(lrow, ko)));
#pragma unroll
            for (int tn = 0; tn < 2; ++tn) {
                bf16x8 bfr = as_frag(*(const int4*)(dW1T + (size_t)(wv * 32 + tn * 16 + lrow) * 128 + ko));
                dacc[tn] = __builtin_amdgcn_mfma_f32_16x16x32_bf16(af, bfr, dacc[tn], 0, 0, 0);
            }
        }
#pragma unroll
        for (int tn = 0; tn < 2; ++tn) {
            const int n = wv * 32 + tn * 16 + lrow;
            const float bias = dec_b1[n];
#pragma unroll
            for (int r = 0; r < 4; ++r)
                buf[sw_off(16 + lq * 4 + r, n)] = f2bf(fast_tanh(dacc[tn][r] + bias));
        }
    }
    __syncthreads();

    // dec layer 2: K=256 -> N=256, in rows 16..31, out rows 32..47
    {
        const f32x4 zero = {0.f, 0.f, 0.f, 0.f};
        f32x4 dacc[2] = {zero, zero};
        const unsigned short* dW2T = wbf + 1212416;
#pragma unroll
        for (int kq = 0; kq < 8; ++kq) {
            const int ko = kq * 32 + lq * 8;
            bf16x8 af = as_frag(*(const int4*)(buf + sw_off(16 + lrow, ko)));
#pragma unroll
            for (int tn = 0; tn < 2; ++tn) {
                bf16x8 bfr = as_frag(*(const int4*)(dW2T + (size_t)(wv * 32 + tn * 16 + lrow) * 256 + ko));
                dacc[tn] = __builtin_amdgcn_mfma_f32_16x16x32_bf16(af, bfr, dacc[tn], 0, 0, 0);
            }
        }
#pragma unroll
        for (int tn = 0; tn < 2; ++tn) {
            const int n = wv * 32 + tn * 16 + lrow;
            const float bias = dec_b2[n];
#pragma unroll
            for (int r = 0; r < 4; ++r)
                buf[sw_off(32 + lq * 4 + r, n)] = f2bf(fast_tanh(dacc[tn][r] + bias));
        }
    }
    __syncthreads();

    // dec layer 3: 256 -> 1, 32 lanes per id, shuffle reduce
    {
        const int m = t >> 5, p = t & 31;
        float sv = 0.f;
#pragma unroll
        for (int i = 0; i < 8; ++i) {
            const int k = p * 8 + i;
            const float a = __uint_as_float((unsigned int)buf[sw_off(32 + m, k)] << 16);
            sv += a * dec_W3[k];
        }
        sv += __shfl_xor(sv, 1);
        sv += __shfl_xor(sv, 2);
        sv += __shfl_xor(sv, 4);
        sv += __shfl_xor(sv, 8);
        sv += __shfl_xor(sv, 16);
        if (p == 0) out[(size_t)(g0 + (m >> 3)) * 8 + (m & 7)] = sv + dec_b3[0];
    }
}

// ---------------------------------------------------------------- launch
extern "C" void kernel_launch(void* const* d_in, const int* in_sizes, int n_in,
                              void* d_out, int out_size, void* d_ws, size_t ws_size,
                              hipStream_t stream) {
    const float* obs    = (const float*)d_in[0];
    const int*   edges  = (const int*)  d_in[1];
    const float* enc_W  = (const float*)d_in[2];
    const float* enc_b  = (const float*)d_in[3];
    const float* msg_W1 = (const float*)d_in[4];
    const float* msg_b1 = (const float*)d_in[5];
    const float* msg_W2 = (const float*)d_in[6];
    const float* msg_b2 = (const float*)d_in[7];
    const float* msg_W3 = (const float*)d_in[8];
    const float* msg_b3 = (const float*)d_in[9];
    const float* gru_Wi = (const float*)d_in[10];
    const float* gru_Wh = (const float*)d_in[11];
    const float* gru_bi = (const float*)d_in[12];
    const float* gru_bh = (const float*)d_in[13];
    const float* dec_W1 = (const float*)d_in[14];
    const float* dec_b1 = (const float*)d_in[15];
    const float* dec_W2 = (const float*)d_in[16];
    const float* dec_b2 = (const float*)d_in[17];
    const float* dec_W3 = (const float*)d_in[18];
    const float* dec_b3 = (const float*)d_in[19];

    unsigned short* wbf = (unsigned short*)d_ws;   // 1277952 bf16

    wt_kernel<<<1277952 / 256, 256, 0, stream>>>(msg_W1, msg_W2, msg_W3, gru_Wi, gru_Wh,
                                                 dec_W1, dec_W2, wbf);
    gnn_fused<<<BGR / 2, 512, 0, stream>>>(
        obs, edges, enc_W, enc_b, wbf,
        msg_b1, msg_b2, msg_b3, gru_bi, gru_bh,
        dec_b1, dec_b2, dec_W3, dec_b3, (float*)d_out);
}

// Round 8
// 1870.588 us; speedup vs baseline: 1.9379x; 1.0076x over previous
//
#include <hip/hip_runtime.h>
#include <hip/hip_bf16.h>
#include <math.h>

#define BGR   8192        // graphs
#define NND   9           // nodes per graph
#define BN    73728       // BGR*NND
#define H     128
#define MH    256
#define FIN   15

typedef __bf16 bf16_t;
typedef bf16_t bf16x8 __attribute__((ext_vector_type(8)));
typedef float  f32x4  __attribute__((ext_vector_type(4)));
typedef float  f32x16 __attribute__((ext_vector_type(16)));

__device__ __forceinline__ unsigned short f2bf(float f) {
    unsigned int u = __float_as_uint(f);
    u += 0x7fff + ((u >> 16) & 1);           // RNE (inputs are finite)
    return (unsigned short)(u >> 16);
}
__device__ __forceinline__ unsigned int pkbf(float a, float b) {
    union { __hip_bfloat162 h; unsigned int u; } un;
    un.h = __float22bfloat162_rn(make_float2(a, b));
    return un.u;
}
__device__ __forceinline__ bf16x8 as_frag(int4 v) {
    union { int4 i; bf16x8 f; } u; u.i = v; return u.f;
}
__device__ __forceinline__ float fast_tanh(float v) {
    float e = __expf(2.0f * v);
    return 1.0f - __fdividef(2.0f, e + 1.0f);
}
__device__ __forceinline__ float fast_sig(float v) {
    return __fdividef(1.0f, 1.0f + __expf(-v));
}
// 16-deep XOR swizzle for 32-row MFMA fragments (2 lanes/bank = free)
__device__ __forceinline__ int sw16(int m, int k) {
    return m * 256 + ((((k >> 3) ^ (m & 15)) << 3) | (k & 7));
}
// 8-deep swizzle (16x16 kernels: gru, dec)
__device__ __forceinline__ int sw_off(int m, int k) {
    return m * 256 + ((((k >> 3) ^ (m & 7)) << 3) | (k & 7));
}

// ---------------------------------------------------------------- deg kernel
__global__ void deg_kernel(const int* __restrict__ edges, float* __restrict__ inv_deg) {
    int g = blockIdx.x * 256 + threadIdx.x;
    if (g >= BGR) return;
    int cnt[NND];
#pragma unroll
    for (int n = 0; n < NND; ++n) cnt[n] = 1;   // self loop
    for (int j = 0; j < 16; ++j) {
        int d = edges[g * 32 + 16 + j];
#pragma unroll
        for (int n = 0; n < NND; ++n) cnt[n] += (d == n) ? 1 : 0;
    }
#pragma unroll
    for (int n = 0; n < NND; ++n) inv_deg[g * NND + n] = 1.0f / (float)cnt[n];
}

// ---------------------------------------------------------------- encoder
__global__ void enc_kernel(const float* __restrict__ obs, const float* __restrict__ W,
                           const float* __restrict__ b, float* __restrict__ x) {
    int tid = blockIdx.x * 256 + threadIdx.x;     // BN*128 threads
    int i = tid >> 7, h = tid & 127;
    float acc = b[h];
#pragma unroll
    for (int k = 0; k < FIN; ++k) acc += obs[i * FIN + k] * W[k * H + h];
    x[i * H + h] = tanhf(acc);
}

// ---------------------------------------------------------------- weight transpose+bf16
// out: [W1T 4x256x256][W2T 4x256x256][W3T 4x128x256][WG 4x512x256][dW1T 256x128][dW2T 256x256]
// WG packed col p = w*64 + gate*16 + c  ->  (gate, h = w*16 + c), w=0..7
__global__ void wt_kernel(const float* __restrict__ W1, const float* __restrict__ W2,
                          const float* __restrict__ W3, const float* __restrict__ Wi,
                          const float* __restrict__ Wh, const float* __restrict__ dW1,
                          const float* __restrict__ dW2, unsigned short* __restrict__ out) {
    int idx = blockIdx.x * 256 + threadIdx.x;     // 1277952 total
    float v;
    if (idx < 262144) {
        int s = idx >> 16, r = idx & 65535, n = r >> 8, k = r & 255;
        v = W1[(s << 16) + (k << 8) + n];
    } else if (idx < 524288) {
        int i2 = idx - 262144;
        int s = i2 >> 16, r = i2 & 65535, n = r >> 8, k = r & 255;
        v = W2[(s << 16) + (k << 8) + n];
    } else if (idx < 655360) {
        int i3 = idx - 524288;
        int s = i3 >> 15, r = i3 & 32767, n = r >> 8, k = r & 255;
        v = W3[(s << 15) + (k << 7) + n];
    } else if (idx < 1179648) {
        int i4 = idx - 655360;                    // 0..524287
        int s = i4 >> 17, rr = i4 & 131071;
        int p = rr >> 8, k = rr & 255;
        int w = p >> 6, rem = p & 63;
        int gate = rem >> 4, c = rem & 15;
        int h = w * 16 + c;
        const int sb = s * 49152;                 // 128*384
        if (gate == 0)      v = (k < 128) ? Wi[sb + k * 384 + h]       : Wh[sb + (k - 128) * 384 + h];
        else if (gate == 1) v = (k < 128) ? Wi[sb + k * 384 + 128 + h] : Wh[sb + (k - 128) * 384 + 128 + h];
        else if (gate == 2) v = (k < 128) ? Wi[sb + k * 384 + 256 + h] : 0.f;
        else                v = (k < 128) ? 0.f                        : Wh[sb + (k - 128) * 384 + 256 + h];
    } else if (idx < 1212416) {
        int i5 = idx - 1179648;                   // dW1T [256][128]
        int n = i5 >> 7, k = i5 & 127;
        v = dW1[k * 256 + n];
    } else {
        int i6 = idx - 1212416;                   // dW2T [256][256]
        int n = i6 >> 8, k = i6 & 255;
        v = dW2[k * 256 + n];
    }
    out[idx] = f2bf(v);
}

// ---------------------------------------------------------------- msg MLP, 32x32x16 MFMA bf16
// ONE graph / block (32 rows: 16 edges + 9 self loops + 7 pad), 256 threads
// = 4 waves. Double-buffered LDS = 2 x 16 KB = exactly 32 KB -> 5 blocks/CU
// (160/32) = 20 waves/CU = 5 waves/SIMD (vs 4 at the 64-row/512-thread
// shape) with five independent barrier groups. Proven spill-free recipe
// kept: dbuf (no barrier inside accumulator liveness), (256,4) = 128-reg
// cap, ~70 unified regs natural. Cost: weight panel read per-32-rows
// (2x L2 weight traffic, ~affordable) traded for +25% latency hiding.
// L1/L2: wave wv owns cols wv*64..+63 (2 n-tiles, shared A-frag).
// L3: wave owns n = wv*32..+31; 9-bin register reduce (bins recomputed
// from edges - no sbin LDS, keeps LDS at exactly 32 KB); plain stores of
// aggr*inv_deg. Zero atomics. 32x32 C-layout: col=lane&31,
// row=(reg&3)+8*(reg>>2)+4*(lane>>5) [HW-verified m74/m101].
__global__ __launch_bounds__(256, 4) void msg_mfma(
        const float* __restrict__ x, const int* __restrict__ edges,
        const unsigned short* __restrict__ W1T, const float* __restrict__ b1,
        const unsigned short* __restrict__ W2T, const float* __restrict__ b2,
        const unsigned short* __restrict__ W3T, const float* __restrict__ inv_deg,
        float* __restrict__ aggr) {
    __shared__ unsigned short bufA[32 * 256];   // 16 KB
    __shared__ unsigned short bufB[32 * 256];   // 16 KB
    const int t  = threadIdx.x;
    const int g  = blockIdx.x;
    const int wv = t >> 6;        // 0..3
    const int ln = t & 63;
    const int l31 = ln & 31;
    const int lh  = ln >> 5;      // k-half selector

    // ---- stage A0 = bf16(concat(x[dst], x[src])) into bufA (pad rows = 0)
    {
        const int rs   = t >> 2;          // 0..63
        const int q    = t & 3;
        const int e    = rs & 31;         // row in block
        const int side = rs >> 5;         // 0 -> dst cols 0..127, 1 -> src cols 128..255
        const int kbase = side * 128 + q * 32;
        if (e < 25) {
            int node;
            if (e < 16) node = g * NND + (side ? edges[g * 32 + e] : edges[g * 32 + 16 + e]);
            else        node = g * NND + (e - 16);
            const float* xs = x + (size_t)node * H + q * 32;
#pragma unroll
            for (int i = 0; i < 8; ++i) {
                float4 v = *(const float4*)(xs + i * 4);
                uint2 o;
                o.x = pkbf(v.x, v.y); o.y = pkbf(v.z, v.w);
                *(uint2*)(bufA + sw16(e, kbase + i * 4)) = o;
            }
        } else {
            uint2 o; o.x = 0u; o.y = 0u;
#pragma unroll
            for (int i = 0; i < 8; ++i)
                *(uint2*)(bufA + sw16(e, kbase + i * 4)) = o;
        }
    }
    __syncthreads();   // B1

    // ---- layer 1: read bufA, write bufB. wave wv -> cols wv*64..+63
    {
        f32x16 acc0, acc1;
#pragma unroll
        for (int i = 0; i < 16; ++i) { acc0[i] = 0.f; acc1[i] = 0.f; }
        const unsigned short* wp0 = W1T + (size_t)(wv * 64 + l31) * 256 + lh * 8;
        const unsigned short* wp1 = wp0 + 32 * 256;
#pragma unroll
        for (int ks = 0; ks < 16; ++ks) {
            const int kk = ks * 16 + lh * 8;
            bf16x8 a  = as_frag(*(const int4*)(bufA + sw16(l31, kk)));
            bf16x8 w0 = as_frag(*(const int4*)(wp0 + ks * 16));
            bf16x8 w1 = as_frag(*(const int4*)(wp1 + ks * 16));
            acc0 = __builtin_amdgcn_mfma_f32_32x32x16_bf16(a, w0, acc0, 0, 0, 0);
            acc1 = __builtin_amdgcn_mfma_f32_32x32x16_bf16(a, w1, acc1, 0, 0, 0);
        }
        const int n = wv * 64 + l31;
        const float bias0 = b1[n], bias1 = b1[n + 32];
#pragma unroll
        for (int reg = 0; reg < 16; ++reg) {
            const int mrow = (reg & 3) + ((reg >> 2) << 3) + (lh << 2);
            bufB[sw16(mrow, n)]      = f2bf(fast_tanh(acc0[reg] + bias0));
            bufB[sw16(mrow, n + 32)] = f2bf(fast_tanh(acc1[reg] + bias1));
        }
    }
    __syncthreads();   // B2

    // ---- layer 2: read bufB, write bufA
    {
        f32x16 acc0, acc1;
#pragma unroll
        for (int i = 0; i < 16; ++i) { acc0[i] = 0.f; acc1[i] = 0.f; }
        const unsigned short* wp0 = W2T + (size_t)(wv * 64 + l31) * 256 + lh * 8;
        const unsigned short* wp1 = wp0 + 32 * 256;
#pragma unroll
        for (int ks = 0; ks < 16; ++ks) {
            const int kk = ks * 16 + lh * 8;
            bf16x8 a  = as_frag(*(const int4*)(bufB + sw16(l31, kk)));
            bf16x8 w0 = as_frag(*(const int4*)(wp0 + ks * 16));
            bf16x8 w1 = as_frag(*(const int4*)(wp1 + ks * 16));
            acc0 = __builtin_amdgcn_mfma_f32_32x32x16_bf16(a, w0, acc0, 0, 0, 0);
            acc1 = __builtin_amdgcn_mfma_f32_32x32x16_bf16(a, w1, acc1, 0, 0, 0);
        }
        const int n = wv * 64 + l31;
        const float bias0 = b2[n], bias1 = b2[n + 32];
#pragma unroll
        for (int reg = 0; reg < 16; ++reg) {
            const int mrow = (reg & 3) + ((reg >> 2) << 3) + (lh << 2);
            bufA[sw16(mrow, n)]      = f2bf(fast_tanh(acc0[reg] + bias0));
            bufA[sw16(mrow, n + 32)] = f2bf(fast_tanh(acc1[reg] + bias1));
        }
    }
    __syncthreads();   // B3

    // ---- layer 3: read bufA; N=128; wave wv -> n = wv*32..+31;
    //      9-bin register reduce, plain scaled stores (no atomics)
    {
        const int n = wv * 32 + l31;
        f32x16 acc;
#pragma unroll
        for (int i = 0; i < 16; ++i) acc[i] = 0.f;
        const unsigned short* wp = W3T + (size_t)n * 256 + lh * 8;
#pragma unroll
        for (int ks = 0; ks < 16; ++ks) {
            const int kk = ks * 16 + lh * 8;
            bf16x8 a  = as_frag(*(const int4*)(bufA + sw16(l31, kk)));
            bf16x8 bw = as_frag(*(const int4*)(wp + ks * 16));
            acc = __builtin_amdgcn_mfma_f32_32x32x16_bf16(a, bw, acc, 0, 0, 0);
        }
        // bin ids for the 16 rows this lane's regs cover (broadcast L1-hot loads)
        int binr[16];
#pragma unroll
        for (int reg = 0; reg < 16; ++reg) {
            const int mrow = (reg & 3) + ((reg >> 2) << 3) + (lh << 2);
            binr[reg] = (mrow < 16) ? edges[g * 32 + 16 + mrow]
                      : ((mrow < 25) ? (mrow - 16) : -1);
        }
#pragma unroll
        for (int b = 0; b < NND; ++b) {
            float s = 0.f;
#pragma unroll
            for (int reg = 0; reg < 16; ++reg)
                s = (binr[reg] == b) ? s + acc[reg] : s;
            s += __shfl_xor(s, 32);     // combine the two lh-halves (rows)
            if (lh == (b & 1)) {
                const int node = g * NND + b;
                aggr[(size_t)node * H + n] = s * inv_deg[node];
            }
        }
    }
}

// ---------------------------------------------------------------- GRU via MFMA (64 nodes / block, 512 thr)
// Wave w owns packed cols w*64..w*64+63 = all 4 gates of h-slice w*16..w*16+15.
// aggr arrives already degree-scaled (msg_mfma folds inv_deg).
__global__ __launch_bounds__(512, 4) void gru_mfma(
        float* __restrict__ x, const float* __restrict__ aggr,
        const unsigned short* __restrict__ WG, const float* __restrict__ b3m,
        const float* __restrict__ bi, const float* __restrict__ bh) {
    __shared__ unsigned short bufA[64 * 256];   // 32 KB
    const int t = threadIdx.x;
    const int n0 = blockIdx.x * 64;
    const int wv = t >> 6, ln = t & 63, lrow = ln & 15, lq = ln >> 4;

    // stage A = bf16([aggr + b3 | x]): m = t>>3, k-slice q*32
    {
        const int m = t >> 3;
        const int q = t & 7;
        const int k0 = q * 32;
        const int node = n0 + m;
        if (q < 4) {
            const float* src = aggr + (size_t)node * H + k0;
#pragma unroll
            for (int i = 0; i < 8; ++i) {
                float4 v = *(const float4*)(src + i * 4);
                const float4 bb = *(const float4*)(b3m + k0 + i * 4);
                v.x = v.x + bb.x; v.y = v.y + bb.y;
                v.z = v.z + bb.z; v.w = v.w + bb.w;
                uint2 o; o.x = pkbf(v.x, v.y); o.y = pkbf(v.z, v.w);
                *(uint2*)(bufA + sw_off(m, k0 + i * 4)) = o;
            }
        } else {
            const float* src = x + (size_t)node * H + (k0 - 128);
#pragma unroll
            for (int i = 0; i < 8; ++i) {
                float4 v = *(const float4*)(src + i * 4);
                uint2 o; o.x = pkbf(v.x, v.y); o.y = pkbf(v.z, v.w);
                *(uint2*)(bufA + sw_off(m, k0 + i * 4)) = o;
            }
        }
    }
    __syncthreads();

    const f32x4 zero = {0.f, 0.f, 0.f, 0.f};
    f32x4 acc[4][4];    // [m-tile][gate]
#pragma unroll
    for (int i = 0; i < 4; ++i)
#pragma unroll
        for (int j = 0; j < 4; ++j) acc[i][j] = zero;

    const unsigned short* wgp = WG + (size_t)(wv * 64 + lrow) * 256;
#pragma unroll
    for (int kq = 0; kq < 8; ++kq) {
        const int ko = kq * 32 + lq * 8;
        bf16x8 af[4], bfr[4];
#pragma unroll
        for (int tm = 0; tm < 4; ++tm)
            af[tm] = as_frag(*(const int4*)(bufA + sw_off(tm * 16 + lrow, ko)));
#pragma unroll
        for (int g = 0; g < 4; ++g)
            bfr[g] = as_frag(*(const int4*)(wgp + (size_t)g * 16 * 256 + ko));
#pragma unroll
        for (int tm = 0; tm < 4; ++tm)
#pragma unroll
            for (int g = 0; g < 4; ++g)
                acc[tm][g] = __builtin_amdgcn_mfma_f32_16x16x32_bf16(af[tm], bfr[g], acc[tm][g], 0, 0, 0);
    }

    // epilogue: thread-local gate mixing for h = wv*16 + lrow
    {
        const int h = wv * 16 + lrow;
        const float b_r = bi[h] + bh[h];
        const float b_z = bi[128 + h] + bh[128 + h];
        const float b_n = bi[256 + h];
        const float b_h = bh[256 + h];
#pragma unroll
        for (int tm = 0; tm < 4; ++tm) {
#pragma unroll
            for (int r = 0; r < 4; ++r) {
                const int node = n0 + tm * 16 + lq * 4 + r;
                const float irhr = acc[tm][0][r] + b_r;
                const float izhz = acc[tm][1][r] + b_z;
                const float inn  = acc[tm][2][r] + b_n;
                const float hn   = acc[tm][3][r] + b_h;
                const float rg = fast_sig(irhr);
                const float zg = fast_sig(izhz);
                const float ng = fast_tanh(inn + rg * hn);
                const float xo = x[(size_t)node * H + h];
                x[(size_t)node * H + h] = (1.f - zg) * ng + zg * xo;
            }
        }
    }
}

// ---------------------------------------------------------------- decoder via MFMA (64 masked ids / block)
__global__ __launch_bounds__(256, 4) void dec_mfma(
        const float* __restrict__ x,
        const unsigned short* __restrict__ W1T, const float* __restrict__ b1,
        const unsigned short* __restrict__ W2T, const float* __restrict__ b2,
        const float* __restrict__ W3, const float* __restrict__ b3,
        float* __restrict__ out) {
    __shared__ unsigned short buf[64 * 256];   // 32 KB
    const int t = threadIdx.x;
    const int id0 = blockIdx.x * 64;
    const int wv = t >> 6, ln = t & 63, lrow = ln & 15, lq = ln >> 4;
    const int nbase = wv * 64;

    // stage bf16(x) for 64 masked ids into buf[:, 0:128]
    {
        const int m = t >> 2, q = t & 3;
        const int id = id0 + m;
        const int node = (id >> 3) * NND + (id & 7);
        const float* src = x + (size_t)node * H + q * 32;
#pragma unroll
        for (int i = 0; i < 8; ++i) {
            float4 v = *(const float4*)(src + i * 4);
            uint2 o; o.x = pkbf(v.x, v.y); o.y = pkbf(v.z, v.w);
            *(uint2*)(buf + sw_off(m, q * 32 + i * 4)) = o;
        }
    }
    __syncthreads();

    const f32x4 zero = {0.f, 0.f, 0.f, 0.f};

    // ---- layer 1: K=128 -> 256 cols
    {
        f32x4 acc[4][4];
#pragma unroll
        for (int i = 0; i < 4; ++i)
#pragma unroll
            for (int j = 0; j < 4; ++j) acc[i][j] = zero;
#pragma unroll
        for (int kq = 0; kq < 4; ++kq) {
            const int ko = kq * 32 + lq * 8;
            bf16x8 af[4], bfr[4];
#pragma unroll
            for (int tm = 0; tm < 4; ++tm)
                af[tm] = as_frag(*(const int4*)(buf + sw_off(tm * 16 + lrow, ko)));
#pragma unroll
            for (int tn = 0; tn < 4; ++tn)
                bfr[tn] = as_frag(*(const int4*)(W1T + (size_t)(nbase + tn * 16 + lrow) * 128 + ko));
#pragma unroll
            for (int tm = 0; tm < 4; ++tm)
#pragma unroll
                for (int tn = 0; tn < 4; ++tn)
                    acc[tm][tn] = __builtin_amdgcn_mfma_f32_16x16x32_bf16(af[tm], bfr[tn], acc[tm][tn], 0, 0, 0);
        }
        __syncthreads();
#pragma unroll
        for (int tn = 0; tn < 4; ++tn) {
            const int n = nbase + tn * 16 + lrow;
            const float bias = b1[n];
#pragma unroll
            for (int tm = 0; tm < 4; ++tm)
#pragma unroll
                for (int r = 0; r < 4; ++r) {
                    const int m = tm * 16 + lq * 4 + r;
                    buf[sw_off(m, n)] = f2bf(fast_tanh(acc[tm][tn][r] + bias));
                }
        }
    }
    __syncthreads();

    // ---- layer 2: K=256 -> 256 cols
    {
        f32x4 acc[4][4];
#pragma unroll
        for (int i = 0; i < 4; ++i)
#pragma unroll
            for (int j = 0; j < 4; ++j) acc[i][j] = zero;
#pragma unroll
        for (int kq = 0; kq < 8; ++kq) {
            const int ko = kq * 32 + lq * 8;
            bf16x8 af[4], bfr[4];
#pragma unroll
            for (int tm = 0; tm < 4; ++tm)
                af[tm] = as_frag(*(const int4*)(buf + sw_off(tm * 16 + lrow, ko)));
#pragma unroll
            for (int tn = 0; tn < 4; ++tn)
                bfr[tn] = as_frag(*(const int4*)(W2T + (size_t)(nbase + tn * 16 + lrow) * 256 + ko));
#pragma unroll
            for (int tm = 0; tm < 4; ++tm)
#pragma unroll
                for (int tn = 0; tn < 4; ++tn)
                    acc[tm][tn] = __builtin_amdgcn_mfma_f32_16x16x32_bf16(af[tm], bfr[tn], acc[tm][tn], 0, 0, 0);
        }
        __syncthreads();
#pragma unroll
        for (int tn = 0; tn < 4; ++tn) {
            const int n = nbase + tn * 16 + lrow;
            const float bias = b2[n];
#pragma unroll
            for (int tm = 0; tm < 4; ++tm)
#pragma unroll
                for (int r = 0; r < 4; ++r) {
                    const int m = tm * 16 + lq * 4 + r;
                    buf[sw_off(m, n)] = f2bf(fast_tanh(acc[tm][tn][r] + bias));
                }
        }
    }
    __syncthreads();

    // ---- layer 3: 256 -> 1, 4 threads per id, shuffle reduce
    {
        const int m = t >> 2, p = t & 3;
        float s = 0.f;
#pragma unroll
        for (int i = 0; i < 64; ++i) {
            const int k = p * 64 + i;
            const float a = __uint_as_float((unsigned int)buf[sw_off(m, k)] << 16);
            s += a * W3[k];
        }
        s += __shfl_xor(s, 1);
        s += __shfl_xor(s, 2);
        if (p == 0) out[id0 + m] = s + b3[0];
    }
}

// ---------------------------------------------------------------- launch
extern "C" void kernel_launch(void* const* d_in, const int* in_sizes, int n_in,
                              void* d_out, int out_size, void* d_ws, size_t ws_size,
                              hipStream_t stream) {
    const float* obs    = (const float*)d_in[0];
    const int*   edges  = (const int*)  d_in[1];
    const float* enc_W  = (const float*)d_in[2];
    const float* enc_b  = (const float*)d_in[3];
    const float* msg_W1 = (const float*)d_in[4];
    const float* msg_b1 = (const float*)d_in[5];
    const float* msg_W2 = (const float*)d_in[6];
    const float* msg_b2 = (const float*)d_in[7];
    const float* msg_W3 = (const float*)d_in[8];
    const float* msg_b3 = (const float*)d_in[9];
    const float* gru_Wi = (const float*)d_in[10];
    const float* gru_Wh = (const float*)d_in[11];
    const float* gru_bi = (const float*)d_in[12];
    const float* gru_bh = (const float*)d_in[13];
    const float* dec_W1 = (const float*)d_in[14];
    const float* dec_b1 = (const float*)d_in[15];
    const float* dec_W2 = (const float*)d_in[16];
    const float* dec_b2 = (const float*)d_in[17];
    const float* dec_W3 = (const float*)d_in[18];
    const float* dec_b3 = (const float*)d_in[19];

    float* x       = (float*)d_ws;                 // BN*128
    float* aggr    = x + (size_t)BN * H;           // BN*128
    float* inv_deg = aggr + (size_t)BN * H;        // BN
    unsigned short* wbf = (unsigned short*)(inv_deg + BN);   // 1277952 bf16

    deg_kernel<<<(BGR + 255) / 256, 256, 0, stream>>>(edges, inv_deg);
    wt_kernel<<<1277952 / 256, 256, 0, stream>>>(msg_W1, msg_W2, msg_W3, gru_Wi, gru_Wh,
                                                 dec_W1, dec_W2, wbf);
    enc_kernel<<<BN * H / 256, 256, 0, stream>>>(obs, enc_W, enc_b, x);

    for (int s = 0; s < 4; ++s) {
        const unsigned short* W1T = wbf + (size_t)s * 65536;
        const unsigned short* W2T = wbf + 262144 + (size_t)s * 65536;
        const unsigned short* W3T = wbf + 524288 + (size_t)s * 32768;
        const unsigned short* WGs = wbf + 655360 + (size_t)s * 131072;
        msg_mfma<<<BGR, 256, 0, stream>>>(
            x, edges,
            W1T, msg_b1 + (size_t)s * 256,
            W2T, msg_b2 + (size_t)s * 256,
            W3T, inv_deg,
            aggr);
        gru_mfma<<<BN / 64, 512, 0, stream>>>(
            x, aggr, WGs, msg_b3 + (size_t)s * 128,
            gru_bi + (size_t)s * 384, gru_bh + (size_t)s * 384);
    }

    dec_mfma<<<BGR * 8 / 64, 256, 0, stream>>>(
        x, wbf + 1179648, dec_b1, wbf + 1212416, dec_b2, dec_W3, dec_b3, (float*)d_out);
}